// Round 3
// baseline (289.248 us; speedup 1.0000x reference)
//
#include <hip/hip_runtime.h>

// CTC loss forward DP (Keras ctc_batch_cost), mean over batch.
// B=512, T=512, C=96 (blank=95), L=64. One wave per example; lane i owns
// extended states 2i (blank) and 2i+1 (label i); lane 63 also owns state 128.
//
// R5 — BISECT ROUND. R3 (DMA staging + new math) and R4 (reg staging + new
// math) both returned absmax=inf. This kernel is R2's VERIFIED math,
// byte-identical (original step form, synchronous renorm every 8 steps),
// with ONLY the staging changed:
//   - 16-step chunks; 6 x float4 coalesced loads/lane into a 4-deep register
//     bank ring (chunk c+4 issued at body c => 3 chunks / ~48 steps of global
//     latency hiding; 18-24 loads in flight; compiler-counted vmcnt).
//   - Staged chunk -> 2-slot LDS ring (ds_write_b128, linear), then per-lane
//     label/blank columns gathered via ds_read right before the chunk's steps.
//     Single wave per block: same-wave DS ops are in-order; no barriers.
// If this passes, staging is sound and the R3/R4 bug is in the fma/stale-
// renorm/e-bank structure. If it fails, staging is the bug.

#define B_ 512
#define T_ 512
#define C_ 96
#define L_ 64
#define BLANK_ 95
#define EPSF 1e-7f
#define LN2F 0.69314718055994530942f
#define U_ 16               // time steps per chunk
#define CHF_ (U_ * C_)      // 1536 floats (6144 B) per chunk

template <int N> struct Ic { static constexpr int v = N; };

template <int CTRL>
__device__ __forceinline__ float dpp_mov(float x) {
    // bound_ctrl=true: invalid source lanes read 0 (identity for max of probs,
    // and exactly the "state -1 doesn't exist" boundary for wave_shr:1).
    return __int_as_float(
        __builtin_amdgcn_update_dpp(0, __float_as_int(x), CTRL, 0xF, 0xF, true));
}

// Full-wave max (64 lanes), all-VALU. Result returned wave-uniform (SGPR).
__device__ __forceinline__ float wave_max(float m) {
    m = fmaxf(m, dpp_mov<0x111>(m));  // row_shr:1
    m = fmaxf(m, dpp_mov<0x112>(m));  // row_shr:2
    m = fmaxf(m, dpp_mov<0x114>(m));  // row_shr:4
    m = fmaxf(m, dpp_mov<0x118>(m));  // row_shr:8   -> lane 15+16k = row max
    m = fmaxf(m, dpp_mov<0x142>(m));  // row_bcast:15
    m = fmaxf(m, dpp_mov<0x143>(m));  // row_bcast:31 -> lane 63 = wave max
    return __int_as_float(__builtin_amdgcn_readlane(__float_as_int(m), 63));
}

__launch_bounds__(64, 1)
__global__ void ctc_loss_kernel(const int* __restrict__ y_true,
                                const float* __restrict__ y_pred,
                                float* __restrict__ out) {
    __shared__ alignas(16) float smem[2][CHF_];  // 12 KiB, slot = chunk & 1
    const int b = blockIdx.x;
    const int lane = threadIdx.x;  // 0..63

    // ---- label metadata (identical to R2) ----
    const int yv = y_true[b * L_ + lane];
    const unsigned long long act = __ballot(yv != -1);
    const int len = __popcll(act);        // label length (32..64)
    const int lab = (yv == -1) ? 0 : yv;  // padded like the reference
    const int lab_prev = __shfl_up(lab, 1);
    const bool cs = (lane == 0) ? true : (lab != lab_prev);

    const float4* g4 = (const float4*)(y_pred + (size_t)b * (T_ * C_));

    float4 rb[4][6];       // staging banks: chunk c lives in bank c&3
    float el[U_], eb[U_];  // current chunk's emissions (+EPS pre-added)
    float a_even, a_odd, a128;
    int accum = 0;  // true_alpha = stored * 2^accum

    auto load_chunk = [&](auto BK_, int c) {  // coalesced: 6 x 1 KiB
        constexpr int BK = decltype(BK_)::v;
        const float4* g = g4 + c * (CHF_ / 4) + lane;
#pragma unroll
        for (int i = 0; i < 6; ++i) rb[BK][i] = g[i * 64];
    };
    auto store_chunk = [&](auto BK_, auto SL_) {  // ds_write_b128, linear
        constexpr int BK = decltype(BK_)::v;
        float4* s = (float4*)&smem[decltype(SL_)::v][0];
#pragma unroll
        for (int i = 0; i < 6; ++i) s[i * 64 + lane] = rb[BK][i];
    };
    auto read_emis = [&](auto SL_) {  // per-lane column gathers (+EPS hoisted)
        constexpr int SL = decltype(SL_)::v;
#pragma unroll
        for (int k = 0; k < U_; ++k) {
            el[k] = smem[SL][k * C_ + lab] + EPSF;     // label column
            eb[k] = smem[SL][k * C_ + BLANK_] + EPSF;  // uniform broadcast
        }
    };

    // ---- R2's step, verbatim ----
    auto step = [&](float plv, float pbv) {
        const float po = dpp_mov<0x138>(a_odd);  // wave_shr:1 -> alpha[2*lane-1]
        const float pos = cs ? po : 0.0f;
        const float ne = (a_even + po) * pbv;
        const float no = (a_odd + a_even + pos) * plv;
        a128 = (a128 + a_odd) * pbv;  // meaningful on lane 63 only
        a_even = ne;
        a_odd = no;
    };

    // ---- R2's synchronous renorm, verbatim ----
    auto renorm = [&]() {
        const float mv = wave_max(fmaxf(fmaxf(a_even, a_odd), a128));
        const int e = ((__float_as_int(mv) >> 23) & 0xFF) - 126;
        const int k = 96 - e;
        a_even = ldexpf(a_even, k);
        a_odd  = ldexpf(a_odd, k);
        a128   = ldexpf(a128, k);
        accum -= k;
    };

    // Body for chunk c: stage chunk c regs->LDS (compiler waits its 6 loads,
    // leaving c+1..c+3 in flight), reload the freed bank with chunk c+4,
    // gather emissions, 16 DP steps with renorm every 8.
    auto body = [&](auto CB_, int c, auto LD_) {
        constexpr int CB = decltype(CB_)::v;  // c & 3
        constexpr int SL = CB & 1;            // c & 1
        store_chunk(Ic<CB>{}, Ic<SL>{});
        if constexpr (decltype(LD_)::v) load_chunk(Ic<CB>{}, c + 4);
        read_emis(Ic<SL>{});
#pragma unroll
        for (int k = 0; k < 8; ++k) step(el[k], eb[k]);
        renorm();
#pragma unroll
        for (int k = 8; k < U_; ++k) step(el[k], eb[k]);
        renorm();
    };

    // ---- prologue: fill the ring (chunks 0..3) ----
    load_chunk(Ic<0>{}, 0);
    load_chunk(Ic<1>{}, 1);
    load_chunk(Ic<2>{}, 2);
    load_chunk(Ic<3>{}, 3);

    // ---- chunk 0 inline: stage, reload, gather, init (t=0), steps 1..15 ----
    store_chunk(Ic<0>{}, Ic<0>{});
    load_chunk(Ic<0>{}, 4);
    read_emis(Ic<0>{});
    a_even = (lane == 0) ? eb[0] : 0.0f;  // state 0 (blank)
    a_odd  = (lane == 0) ? el[0] : 0.0f;  // state 1 (label 0)
    a128 = 0.0f;
#pragma unroll
    for (int k = 1; k < 8; ++k) step(el[k], eb[k]);
    renorm();
#pragma unroll
    for (int k = 8; k < U_; ++k) step(el[k], eb[k]);
    renorm();

    // ---- chunks 1..24 ----
    for (int g = 0; g < 6; ++g) {
        const int c0 = 1 + g * 4;
        body(Ic<1>{}, c0 + 0, Ic<1>{});
        body(Ic<2>{}, c0 + 1, Ic<1>{});
        body(Ic<3>{}, c0 + 2, Ic<1>{});
        body(Ic<0>{}, c0 + 3, Ic<1>{});
    }
    // ---- chunks 25..31 (last load: body 27 loads chunk 31) ----
    body(Ic<1>{}, 25, Ic<1>{});
    body(Ic<2>{}, 26, Ic<1>{});
    body(Ic<3>{}, 27, Ic<1>{});
    body(Ic<0>{}, 28, Ic<0>{});
    body(Ic<1>{}, 29, Ic<0>{});
    body(Ic<2>{}, 30, Ic<0>{});
    body(Ic<3>{}, 31, Ic<0>{});

    // ---- readout: loss = -ln2 * (log2(a[2len] + a[2len-1]) + accum) ----
    const float al = __shfl(a_odd, len - 1);             // state 2len-1
    const float ab = (len < L_) ? __shfl(a_even, len)    // state 2len
                                : __shfl(a128, 63);      // state 128
    if (lane == 0) {
        const float loss = -LN2F * (log2f(ab + al) + (float)accum);
        atomicAdd(out, loss * (1.0f / B_));
    }
}

extern "C" void kernel_launch(void* const* d_in, const int* in_sizes, int n_in,
                              void* d_out, int out_size, void* d_ws, size_t ws_size,
                              hipStream_t stream) {
    const int* y_true = (const int*)d_in[0];
    const float* y_pred = (const float*)d_in[1];
    float* out = (float*)d_out;
    hipMemsetAsync(out, 0, sizeof(float), stream);
    ctc_loss_kernel<<<B_, 64, 0, stream>>>(y_true, y_pred, out);
}

// Round 4
// 152.990 us; speedup vs baseline: 1.8906x; 1.8906x over previous
//
#include <hip/hip_runtime.h>

// CTC loss forward DP (Keras ctc_batch_cost), mean over batch.
// B=512, T=512, C=96 (blank=95), L=64. One wave per example; lane i owns
// extended states 2i (blank) and 2i+1 (label i); lane 63 also owns state 128.
//
// R6: fix R5's scratch spill. R5's float4 rb[4][6] staging ring went to
// scratch (VGPR_Count=68 < 96 needed; WRITE_SIZE=81MB of spill traffic on a
// 4-byte-output kernel; 180us at 9% HBM). This round:
//   - Staging = 12 INDIVIDUALLY-NAMED float4 registers (s0..s11) holding one
//     32-step chunk (12 KiB/chunk, 12 coalesced dwordx4 loads/lane). Named
//     scalars cannot be demoted to scratch.
//   - Pipeline: at body c, regs hold chunk c+1 (loads issued one body ago);
//     read chunk c's emissions from LDS, ds_write chunk c+1 to the other slot,
//     issue loads for chunk c+2, then 32 DP steps. One body (~600+ cy) covers
//     both global-load and LDS write->read latency.
//   - Math is R2/R5-verified, byte-identical: original step form, synchronous
//     renorm every 8 steps (first at t=7). el[32]/eb[32] scalar arrays with
//     fully-static indexing (proven to stay in VGPRs in R5).

#define B_ 512
#define T_ 512
#define C_ 96
#define L_ 64
#define BLANK_ 95
#define EPSF 1e-7f
#define LN2F 0.69314718055994530942f
#define U_ 32               // time steps per chunk
#define CHF_ (U_ * C_)      // 3072 floats (12 KiB) per chunk
#define NCH_ (T_ / U_)      // 16 chunks

template <int CTRL>
__device__ __forceinline__ float dpp_mov(float x) {
    // bound_ctrl=true: invalid source lanes read 0 (identity for max of probs,
    // and exactly the "state -1 doesn't exist" boundary for wave_shr:1).
    return __int_as_float(
        __builtin_amdgcn_update_dpp(0, __float_as_int(x), CTRL, 0xF, 0xF, true));
}

// Full-wave max (64 lanes), all-VALU. Result returned wave-uniform (SGPR).
__device__ __forceinline__ float wave_max(float m) {
    m = fmaxf(m, dpp_mov<0x111>(m));  // row_shr:1
    m = fmaxf(m, dpp_mov<0x112>(m));  // row_shr:2
    m = fmaxf(m, dpp_mov<0x114>(m));  // row_shr:4
    m = fmaxf(m, dpp_mov<0x118>(m));  // row_shr:8   -> lane 15+16k = row max
    m = fmaxf(m, dpp_mov<0x142>(m));  // row_bcast:15
    m = fmaxf(m, dpp_mov<0x143>(m));  // row_bcast:31 -> lane 63 = wave max
    return __int_as_float(__builtin_amdgcn_readlane(__float_as_int(m), 63));
}

__launch_bounds__(64, 1)
__global__ void ctc_loss_kernel(const int* __restrict__ y_true,
                                const float* __restrict__ y_pred,
                                float* __restrict__ out) {
    __shared__ alignas(16) float smem[2][CHF_];  // 24 KiB, slot = chunk & 1
    const int b = blockIdx.x;
    const int lane = threadIdx.x;  // 0..63

    // ---- label metadata (identical to R2/R5) ----
    const int yv = y_true[b * L_ + lane];
    const unsigned long long act = __ballot(yv != -1);
    const int len = __popcll(act);        // label length (32..64)
    const int lab = (yv == -1) ? 0 : yv;  // padded like the reference
    const int lab_prev = __shfl_up(lab, 1);
    const bool cs = (lane == 0) ? true : (lab != lab_prev);

    const float4* g4 = (const float4*)(y_pred + (size_t)b * (T_ * C_));

    // ---- staging registers: named scalars, cannot spill as an array ----
    float4 s0, s1, s2, s3, s4, s5, s6, s7, s8, s9, s10, s11;
    float el[U_], eb[U_];  // current chunk's emissions (+EPS pre-added)
    float a_even, a_odd, a128;
    int accum = 0;  // true_alpha = stored * 2^accum

    auto load_chunk = [&](int c) {  // 12 x 1 KiB coalesced dwordx4
        const float4* g = g4 + c * (CHF_ / 4) + lane;
        s0 = g[0 * 64];  s1 = g[1 * 64];  s2 = g[2 * 64];  s3 = g[3 * 64];
        s4 = g[4 * 64];  s5 = g[5 * 64];  s6 = g[6 * 64];  s7 = g[7 * 64];
        s8 = g[8 * 64];  s9 = g[9 * 64];  s10 = g[10 * 64]; s11 = g[11 * 64];
    };
    auto store_chunk = [&](int sl) {  // ds_write_b128, linear layout
        float4* s = (float4*)&smem[sl][0] + lane;
        s[0 * 64] = s0;  s[1 * 64] = s1;  s[2 * 64] = s2;  s[3 * 64] = s3;
        s[4 * 64] = s4;  s[5 * 64] = s5;  s[6 * 64] = s6;  s[7 * 64] = s7;
        s[8 * 64] = s8;  s[9 * 64] = s9;  s[10 * 64] = s10; s[11 * 64] = s11;
    };
    auto read_emis = [&](int sl) {  // per-lane column gathers (+EPS hoisted)
        const float* base = &smem[sl][0];
#pragma unroll
        for (int k = 0; k < U_; ++k) {
            el[k] = base[k * C_ + lab] + EPSF;     // label column (~2-way bank)
            eb[k] = base[k * C_ + BLANK_] + EPSF;  // uniform -> LDS broadcast
        }
    };

    // ---- R2's step, verbatim ----
    auto step = [&](float plv, float pbv) {
        const float po = dpp_mov<0x138>(a_odd);  // wave_shr:1 -> alpha[2*lane-1]
        const float pos = cs ? po : 0.0f;
        const float ne = (a_even + po) * pbv;
        const float no = (a_odd + a_even + pos) * plv;
        a128 = (a128 + a_odd) * pbv;  // meaningful on lane 63 only
        a_even = ne;
        a_odd = no;
    };

    // ---- R2's synchronous renorm, verbatim ----
    auto renorm = [&]() {
        const float mv = wave_max(fmaxf(fmaxf(a_even, a_odd), a128));
        const int e = ((__float_as_int(mv) >> 23) & 0xFF) - 126;
        const int k = 96 - e;
        a_even = ldexpf(a_even, k);
        a_odd  = ldexpf(a_odd, k);
        a128   = ldexpf(a128, k);
        accum -= k;
    };

    // Body for chunk c (c >= 1): gather chunk c emissions, stage chunk c+1
    // regs->LDS (compiler-counted vmcnt wait on its 12 loads, issued one body
    // ago), issue loads for chunk c+2, run 32 steps with renorm every 8.
    auto body = [&](int c, bool ld) {
        read_emis(c & 1);
        store_chunk((c + 1) & 1);
        if (ld) load_chunk(c + 2);
#pragma unroll
        for (int k = 0; k < U_; ++k) {
            step(el[k], eb[k]);
            if ((k & 7) == 7) renorm();
        }
    };

    // ---- prologue ----
    load_chunk(0);
    store_chunk(0);   // waits chunk-0 loads
    load_chunk(1);    // in flight across chunk 0's steps
    read_emis(0);

    // ---- chunk 0 inline: init (t=0) + steps 1..31, renorm at 7,15,23,31 ----
    store_chunk(1);   // chunk 1 -> slot 1 (waits its loads)
    load_chunk(2);
    a_even = (lane == 0) ? eb[0] : 0.0f;  // state 0 (blank)
    a_odd  = (lane == 0) ? el[0] : 0.0f;  // state 1 (label 0)
    a128 = 0.0f;
#pragma unroll
    for (int k = 1; k < U_; ++k) {
        step(el[k], eb[k]);
        if ((k & 7) == 7) renorm();
    }

    // ---- chunks 1..14 (last load: body 13 loads chunk 15) ----
    for (int c = 1; c <= 13; ++c) body(c, true);
    body(14, false);

    // ---- chunk 15: steps only ----
    read_emis(1);
#pragma unroll
    for (int k = 0; k < U_; ++k) {
        step(el[k], eb[k]);
        if ((k & 7) == 7) renorm();
    }

    // ---- readout: loss = -ln2 * (log2(a[2len] + a[2len-1]) + accum) ----
    const float al = __shfl(a_odd, len - 1);             // state 2len-1
    const float ab = (len < L_) ? __shfl(a_even, len)    // state 2len
                                : __shfl(a128, 63);      // state 128
    if (lane == 0) {
        const float loss = -LN2F * (log2f(ab + al) + (float)accum);
        atomicAdd(out, loss * (1.0f / B_));
    }
}

extern "C" void kernel_launch(void* const* d_in, const int* in_sizes, int n_in,
                              void* d_out, int out_size, void* d_ws, size_t ws_size,
                              hipStream_t stream) {
    const int* y_true = (const int*)d_in[0];
    const float* y_pred = (const float*)d_in[1];
    float* out = (float*)d_out;
    hipMemsetAsync(out, 0, sizeof(float), stream);
    ctc_loss_kernel<<<B_, 64, 0, stream>>>(y_true, y_pred, out);
}

// Round 7
// 150.801 us; speedup vs baseline: 1.9181x; 1.0145x over previous
//
#include <hip/hip_runtime.h>

// CTC loss forward DP (Keras ctc_batch_cost), mean over batch.
// B=512, T=512, C=96 (blank=95), L=64. One wave per example; lane i owns
// extended states 2i (blank) and 2i+1 (label i); lane 63 also owns state 128.
//
// R9 = R6 VERBATIM (named-register staging -> LDS ring; cndmask step;
// SYNCHRONOUS renorm every 8 — the renorm floor is load-bearing: stale-8 and
// sync-16 variants all inf'd via FTZ of end-state alphas) + ONE isolated
// change: no contended atomic. 512 same-address device-scope atomicAdds from
// near-simultaneously-finishing waves ping-pong one cacheline across 8 XCD
// L2s (~tens of ns each => est. 25-40us tail). Per-block loss -> d_ws
// partials; 1-block tree-reduce kernel writes the mean.

#define B_ 512
#define T_ 512
#define C_ 96
#define L_ 64
#define BLANK_ 95
#define EPSF 1e-7f
#define LN2F 0.69314718055994530942f
#define U_ 32               // time steps per chunk
#define CHF_ (U_ * C_)      // 3072 floats (12 KiB) per chunk
#define NCH_ (T_ / U_)      // 16 chunks

template <int CTRL>
__device__ __forceinline__ float dpp_mov(float x) {
    // bound_ctrl=true: invalid source lanes read 0 (identity for max of probs,
    // and exactly the "state -1 doesn't exist" boundary for wave_shr:1).
    return __int_as_float(
        __builtin_amdgcn_update_dpp(0, __float_as_int(x), CTRL, 0xF, 0xF, true));
}

// Full-wave max (64 lanes), all-VALU. Result returned wave-uniform (SGPR).
__device__ __forceinline__ float wave_max(float m) {
    m = fmaxf(m, dpp_mov<0x111>(m));  // row_shr:1
    m = fmaxf(m, dpp_mov<0x112>(m));  // row_shr:2
    m = fmaxf(m, dpp_mov<0x114>(m));  // row_shr:4
    m = fmaxf(m, dpp_mov<0x118>(m));  // row_shr:8   -> lane 15+16k = row max
    m = fmaxf(m, dpp_mov<0x142>(m));  // row_bcast:15
    m = fmaxf(m, dpp_mov<0x143>(m));  // row_bcast:31 -> lane 63 = wave max
    return __int_as_float(__builtin_amdgcn_readlane(__float_as_int(m), 63));
}

__launch_bounds__(64, 1)
__global__ void ctc_loss_kernel(const int* __restrict__ y_true,
                                const float* __restrict__ y_pred,
                                float* __restrict__ part) {
    __shared__ alignas(16) float smem[2][CHF_];  // 24 KiB, slot = chunk & 1
    const int b = blockIdx.x;
    const int lane = threadIdx.x;  // 0..63

    // ---- label metadata (identical to R2/R6) ----
    const int yv = y_true[b * L_ + lane];
    const unsigned long long act = __ballot(yv != -1);
    const int len = __popcll(act);        // label length (32..64)
    const int lab = (yv == -1) ? 0 : yv;  // padded like the reference
    const int lab_prev = __shfl_up(lab, 1);
    const bool cs = (lane == 0) ? true : (lab != lab_prev);

    const float4* g4 = (const float4*)(y_pred + (size_t)b * (T_ * C_));

    // ---- staging registers: named scalars, cannot spill as an array ----
    float4 s0, s1, s2, s3, s4, s5, s6, s7, s8, s9, s10, s11;
    float el[U_], eb[U_];  // current chunk's emissions (+EPS pre-added)
    float a_even, a_odd, a128;
    int accum = 0;  // true_alpha = stored * 2^accum

    auto load_chunk = [&](int c) {  // 12 x 1 KiB coalesced dwordx4
        const float4* g = g4 + c * (CHF_ / 4) + lane;
        s0 = g[0 * 64];  s1 = g[1 * 64];  s2 = g[2 * 64];  s3 = g[3 * 64];
        s4 = g[4 * 64];  s5 = g[5 * 64];  s6 = g[6 * 64];  s7 = g[7 * 64];
        s8 = g[8 * 64];  s9 = g[9 * 64];  s10 = g[10 * 64]; s11 = g[11 * 64];
    };
    auto store_chunk = [&](int sl) {  // ds_write_b128, linear layout
        float4* s = (float4*)&smem[sl][0] + lane;
        s[0 * 64] = s0;  s[1 * 64] = s1;  s[2 * 64] = s2;  s[3 * 64] = s3;
        s[4 * 64] = s4;  s[5 * 64] = s5;  s[6 * 64] = s6;  s[7 * 64] = s7;
        s[8 * 64] = s8;  s[9 * 64] = s9;  s[10 * 64] = s10; s[11 * 64] = s11;
    };
    auto read_emis = [&](int sl) {  // per-lane column gathers (+EPS hoisted)
        const float* base = &smem[sl][0];
#pragma unroll
        for (int k = 0; k < U_; ++k) {
            el[k] = base[k * C_ + lab] + EPSF;     // label column (~2-way bank)
            eb[k] = base[k * C_ + BLANK_] + EPSF;  // uniform -> LDS broadcast
        }
    };

    // ---- R2/R6's step, verbatim ----
    auto step = [&](float plv, float pbv) {
        const float po = dpp_mov<0x138>(a_odd);  // wave_shr:1 -> alpha[2*lane-1]
        const float pos = cs ? po : 0.0f;
        const float ne = (a_even + po) * pbv;
        const float no = (a_odd + a_even + pos) * plv;
        a128 = (a128 + a_odd) * pbv;  // meaningful on lane 63 only
        a_even = ne;
        a_odd = no;
    };

    // ---- R2/R6's synchronous renorm, verbatim; cadence 8 is FROZEN ----
    auto renorm = [&]() {
        const float mv = wave_max(fmaxf(fmaxf(a_even, a_odd), a128));
        const int e = ((__float_as_int(mv) >> 23) & 0xFF) - 126;
        const int k = 96 - e;
        a_even = ldexpf(a_even, k);
        a_odd  = ldexpf(a_odd, k);
        a128   = ldexpf(a128, k);
        accum -= k;
    };

    // Body for chunk c (c >= 1): gather chunk c emissions, stage chunk c+1
    // regs->LDS (compiler-counted vmcnt wait on its 12 loads, issued one body
    // ago), issue loads for chunk c+2, run 32 steps with renorm every 8.
    auto body = [&](int c, bool ld) {
        read_emis(c & 1);
        store_chunk((c + 1) & 1);
        if (ld) load_chunk(c + 2);
#pragma unroll
        for (int k = 0; k < U_; ++k) {
            step(el[k], eb[k]);
            if ((k & 7) == 7) renorm();
        }
    };

    // ---- prologue ----
    load_chunk(0);
    store_chunk(0);   // waits chunk-0 loads
    load_chunk(1);    // in flight across chunk 0's steps
    read_emis(0);

    // ---- chunk 0 inline: init (t=0) + steps 1..31, renorm at 7,15,23,31 ----
    store_chunk(1);   // chunk 1 -> slot 1 (waits its loads)
    load_chunk(2);
    a_even = (lane == 0) ? eb[0] : 0.0f;  // state 0 (blank)
    a_odd  = (lane == 0) ? el[0] : 0.0f;  // state 1 (label 0)
    a128 = 0.0f;
#pragma unroll
    for (int k = 1; k < U_; ++k) {
        step(el[k], eb[k]);
        if ((k & 7) == 7) renorm();
    }

    // ---- chunks 1..14 (last load: body 13 loads chunk 15) ----
    for (int c = 1; c <= 13; ++c) body(c, true);
    body(14, false);

    // ---- chunk 15: steps only ----
    read_emis(1);
#pragma unroll
    for (int k = 0; k < U_; ++k) {
        step(el[k], eb[k]);
        if ((k & 7) == 7) renorm();
    }

    // ---- readout: loss = -ln2 * (log2(a[2len] + a[2len-1]) + accum) ----
    const float al = __shfl(a_odd, len - 1);             // state 2len-1
    const float ab = (len < L_) ? __shfl(a_even, len)    // state 2len
                                : __shfl(a128, 63);      // state 128
    if (lane == 0) part[b] = -LN2F * (log2f(ab + al) + (float)accum);
}

// 1 block x 512 threads: tree-reduce the per-example losses, write the mean.
__launch_bounds__(512, 1)
__global__ void ctc_reduce_kernel(const float* __restrict__ part,
                                  float* __restrict__ out) {
    __shared__ float sm[B_];
    const int t = threadIdx.x;
    sm[t] = part[t];
    __syncthreads();
#pragma unroll
    for (int s = B_ / 2; s > 0; s >>= 1) {
        if (t < s) sm[t] += sm[t + s];
        __syncthreads();
    }
    if (t == 0) out[0] = sm[0] * (1.0f / B_);
}

extern "C" void kernel_launch(void* const* d_in, const int* in_sizes, int n_in,
                              void* d_out, int out_size, void* d_ws, size_t ws_size,
                              hipStream_t stream) {
    const int* y_true = (const int*)d_in[0];
    const float* y_pred = (const float*)d_in[1];
    float* part = (float*)d_ws;  // B_ floats of per-example losses
    float* out = (float*)d_out;
    ctc_loss_kernel<<<B_, 64, 0, stream>>>(y_true, y_pred, part);
    ctc_reduce_kernel<<<1, B_, 0, stream>>>(part, out);
}